// Round 2
// 265.059 us; speedup vs baseline: 1.5910x; 1.5910x over previous
//
#include <hip/hip_runtime.h>
#include <math.h>

#define DIM    96
#define HEADS  3
#define NTOK   49
#define NWIN   64
#define SCALE  0.17677669529663687f

// ---- workspace layout (bytes) ----
// MODE 2: qkv_wb bf16 @0 (55296) | proj_wb bf16 @55296 (18432) | fused tab [64][3][49][49] f32 @73728 (1844352)
// MODE 1: qkv_wb bf16 @0         | proj_wb bf16 @55296         | bias tab [3][49][49] f32 @73728 (28812)
// MODE 0: bias tab [3][49][49] f32 @0 (28812)   -- footprint of the previously-verified kernel
#define PROJWB_OFFB 55296
#define TAB_OFFB    73728
#define FUSED_TAB_ELEMS (NWIN * HEADS * NTOK * NTOK)
#define BIAS_TAB_ELEMS  (HEADS * NTOK * NTOK)
#define WS_MODE2_NEED (TAB_OFFB + FUSED_TAB_ELEMS * 4)
#define WS_MODE1_NEED (TAB_OFFB + BIAS_TAB_ELEMS * 4)

// ---- LDS layout (unsigned short indices), all XOR-swizzled ----
// K   [3][64][32] @ 0      (6144)  token-major per head
// VT  [3][32][64] @ 6144   (6144)  d-major (tokens inner)
// SCR [4][1024]   @ 12288  (4096)  per-wave transpose scratch (Q/P/O)
// total: 16384 shorts = 32768 B -> 5 blocks/CU
#define K_OFF   0
#define VT_OFF  6144
#define SCR_OFF 12288
#define LDS_SHORTS 16384

typedef float  f32x4  __attribute__((ext_vector_type(4)));
typedef __bf16 bf16x8 __attribute__((ext_vector_type(8)));
typedef short  short8 __attribute__((ext_vector_type(8)));

union U8 { short8 s; bf16x8 b; };

#define LGKM0() asm volatile("s_waitcnt lgkmcnt(0)" ::: "memory")

// XOR-swizzle on short index: XOR 16B-granule bits [5:3] with 128B-line bits [8:6].
// All region bases are 512-short aligned, so relative==absolute for the XOR'd bits.
__device__ __forceinline__ int swz(int s) { return s ^ ((s >> 3) & 56); }

__device__ __forceinline__ unsigned short f2bf(float f) {
    __bf16 h = (__bf16)f;
    union { __bf16 h; unsigned short u; } v; v.h = h; return v.u;
}

// load 8 consecutive f32 from global, convert to bf16 frag
__device__ __forceinline__ void ldcvt_g(const float* __restrict__ p, U8& u) {
    float4 f0 = *(const float4*)p;
    float4 f1 = *(const float4*)(p + 4);
    u.b[0] = (__bf16)f0.x; u.b[1] = (__bf16)f0.y; u.b[2] = (__bf16)f0.z; u.b[3] = (__bf16)f0.w;
    u.b[4] = (__bf16)f1.x; u.b[5] = (__bf16)f1.y; u.b[6] = (__bf16)f1.z; u.b[7] = (__bf16)f1.w;
}

// ---- prepass ----
__global__ __launch_bounds__(256)
void prep(const float* __restrict__ rpb, const int* __restrict__ rel,
          const float* __restrict__ mask,
          const float* __restrict__ qkv_w, const float* __restrict__ proj_w,
          unsigned short* __restrict__ qkv_wb, unsigned short* __restrict__ proj_wb,
          float* __restrict__ tab, int mode)
{
    int t = blockIdx.x * 256 + threadIdx.x;
    if (mode >= 1) {
        if (t < 3 * DIM * DIM) qkv_wb[t] = f2bf(qkv_w[t]);
        if (t < DIM * DIM)     proj_wb[t] = f2bf(proj_w[t]);
    }
    if (mode == 2) {
        if (t < FUSED_TAB_ELEMS) {
            int win = t / (HEADS * NTOK * NTOK);
            int rem = t - win * (HEADS * NTOK * NTOK);
            int h   = rem / (NTOK * NTOK);
            int ij  = rem - h * (NTOK * NTOK);
            tab[t] = rpb[rel[ij] * HEADS + h] + mask[win * (NTOK * NTOK) + ij];
        }
    } else if (t < BIAS_TAB_ELEMS) {
        int h = t / (NTOK * NTOK), ij = t - h * (NTOK * NTOK);
        tab[t] = rpb[rel[ij] * HEADS + h];
    }
}

// weight fragment load: bf16 from workspace (MODE>=1) or f32+convert (MODE 0)
template<int MODE>
__device__ __forceinline__ void ldw(const unsigned short* __restrict__ wb,
                                    const float* __restrict__ wf, int idx, U8& u) {
    if constexpr (MODE >= 1) u.s = *(const short8*)(wb + idx);
    else                     ldcvt_g(wf + idx, u);
}

template<int MODE>
__global__ __launch_bounds__(256, 5)
void winattn(const float* __restrict__ x,
             const float* __restrict__ mask,
             const float* __restrict__ qkv_w,
             const float* __restrict__ qkv_b,
             const float* __restrict__ proj_w,
             const float* __restrict__ proj_b,
             const unsigned short* __restrict__ qkv_wb,
             const unsigned short* __restrict__ proj_wb,
             const float* __restrict__ tab,
             float* __restrict__ out)
{
    __shared__ __align__(16) unsigned short sbuf[LDS_SHORTS];

    const int tid  = threadIdx.x;
    const int lane = tid & 63;
    const int wave = __builtin_amdgcn_readfirstlane(tid >> 6);
    const int l15  = lane & 15;
    const int quad = lane >> 4;
    const int bnw  = blockIdx.x;
    const int win  = bnw & (NWIN - 1);
    const int scrb = SCR_OFF + wave * 1024;   // per-wave scratch

    // ================= Phase 1: QKV = x @ qkv_w^T + b =================
    // Wave w is the m-tile for tokens 16w..16w+15.
    U8 af[3];
    {
        const float* xw = x + (size_t)bnw * (NTOK * DIM);
        const int arow = 16 * wave + l15;
        const bool av = (arow < NTOK);
        #pragma unroll
        for (int s = 0; s < 3; ++s) {
            if (av) ldcvt_g(xw + arow * DIM + 32 * s + quad * 8, af[s]);
            else {
                #pragma unroll
                for (int j = 0; j < 8; ++j) af[s].b[j] = (__bf16)0.0f;
            }
        }
    }

    // --- Q tiles (t=0..5): through per-wave scratch -> A-frags in regs ---
    U8 qfrag[3];
    #pragma unroll
    for (int h = 0; h < 3; ++h) {
        #pragma unroll
        for (int half = 0; half < 2; ++half) {
            const int col = 16 * (2 * h + half) + l15;
            f32x4 acc = {0.f, 0.f, 0.f, 0.f};
            #pragma unroll
            for (int s = 0; s < 3; ++s) {
                U8 b; ldw<MODE>(qkv_wb, qkv_w, col * DIM + 32 * s + quad * 8, b);
                acc = __builtin_amdgcn_mfma_f32_16x16x32_bf16(af[s].b, b.b, acc, 0, 0, 0);
            }
            const float bb = qkv_b[col];
            #pragma unroll
            for (int r = 0; r < 4; ++r)
                sbuf[swz(scrb + (quad * 4 + r) * 32 + half * 16 + l15)] =
                    f2bf((acc[r] + bb) * SCALE);
        }
        LGKM0();
        qfrag[h].s = *(const short8*)(sbuf + swz(scrb + l15 * 32 + quad * 8));
        LGKM0();   // retire read before next h reuses scratch
    }

    // --- K tiles (t=6..11): token-major into swizzled LDS ---
    #pragma unroll
    for (int tk = 0; tk < 6; ++tk) {
        const int col = 16 * (tk + 6) + l15;
        f32x4 acc = {0.f, 0.f, 0.f, 0.f};
        #pragma unroll
        for (int s = 0; s < 3; ++s) {
            U8 b; ldw<MODE>(qkv_wb, qkv_w, col * DIM + 32 * s + quad * 8, b);
            acc = __builtin_amdgcn_mfma_f32_16x16x32_bf16(af[s].b, b.b, acc, 0, 0, 0);
        }
        const float bb = qkv_b[col];
        const int c = col - DIM, h = c >> 5, d = c & 31;
        #pragma unroll
        for (int r = 0; r < 4; ++r) {
            const int row = 16 * wave + quad * 4 + r;
            sbuf[swz(K_OFF + h * 2048 + row * 32 + d)] = f2bf(acc[r] + bb);
        }
    }

    // --- V tiles (t=12..17): transposed [h][d][token] into swizzled LDS ---
    #pragma unroll
    for (int tv = 0; tv < 6; ++tv) {
        const int col = 16 * (tv + 12) + l15;
        f32x4 acc = {0.f, 0.f, 0.f, 0.f};
        #pragma unroll
        for (int s = 0; s < 3; ++s) {
            U8 b; ldw<MODE>(qkv_wb, qkv_w, col * DIM + 32 * s + quad * 8, b);
            acc = __builtin_amdgcn_mfma_f32_16x16x32_bf16(af[s].b, b.b, acc, 0, 0, 0);
        }
        const float bb = qkv_b[col];
        const int c = col - 2 * DIM, h = c >> 5, d = c & 31;
        const int row0 = 16 * wave + quad * 4;
        ushort4 pk;
        pk.x = f2bf(acc[0] + bb); pk.y = f2bf(acc[1] + bb);
        pk.z = f2bf(acc[2] + bb); pk.w = f2bf(acc[3] + bb);
        *(ushort4*)(sbuf + swz(VT_OFF + h * 2048 + d * 64 + row0)) = pk;
    }

    __syncthreads();   // the ONLY barrier: K and VT visible to all waves

    // ====== Phase 2+3 (per head): S = QK^T + bias+mask, neg-softmax, O = P V ======
    // Wave w owns row-tile mt=w for all 3 heads -> Q/P/O stay within the wave.
    U8 af4[3];
    #pragma unroll
    for (int h = 0; h < 3; ++h) {
        // S tiles
        f32x4 st[4];
        #pragma unroll
        for (int t = 0; t < 4; ++t) {
            U8 kf; kf.s = *(const short8*)(sbuf + swz(K_OFF + h * 2048 + (16 * t + l15) * 32 + quad * 8));
            f32x4 z = {0.f, 0.f, 0.f, 0.f};
            st[t] = __builtin_amdgcn_mfma_f32_16x16x32_bf16(qfrag[h].b, kf.b, z, 0, 0, 0);
        }
        const float* fm = (MODE == 2) ? (tab + (size_t)(win * HEADS + h) * (NTOK * NTOK))
                                      : (tab + h * (NTOK * NTOK));
        const float* mw = mask + (size_t)win * (NTOK * NTOK);

        float sv[4][4];
        float mx[4] = {-1e30f, -1e30f, -1e30f, -1e30f};
        bool cok[4];
        #pragma unroll
        for (int t = 0; t < 4; ++t) {
            const int colr = 16 * t + l15;
            cok[t] = (colr < NTOK);
            const int colc = cok[t] ? colr : (NTOK - 1);
            #pragma unroll
            for (int r = 0; r < 4; ++r) {
                const int rowr = 16 * wave + quad * 4 + r;
                const int rowc = (rowr < NTOK) ? rowr : (NTOK - 1);
                float s = st[t][r] + fm[rowc * NTOK + colc];
                if constexpr (MODE != 2) s += mw[rowc * NTOK + colc];
                sv[t][r] = s;
                float aa = cok[t] ? fabsf(s) : -1e30f;
                mx[r] = fmaxf(mx[r], aa);
            }
        }
        #pragma unroll
        for (int r = 0; r < 4; ++r) {
            #pragma unroll
            for (int m = 1; m < 16; m <<= 1)
                mx[r] = fmaxf(mx[r], __shfl_xor(mx[r], m));
        }
        // exp + sign, write P directly to scratch (unnormalized), accumulate sum
        float sum[4] = {0.f, 0.f, 0.f, 0.f};
        #pragma unroll
        for (int t = 0; t < 4; ++t) {
            #pragma unroll
            for (int r = 0; r < 4; ++r) {
                const float s = sv[t][r];
                const float e = cok[t] ? __expf(fabsf(s) - mx[r]) : 0.f;
                sum[r] += e;
                const float p = (s > 0.f) ? e : ((s < 0.f) ? -e : 0.f);
                sbuf[swz(scrb + (quad * 4 + r) * 64 + 16 * t + l15)] = f2bf(p);
            }
        }
        float invl[4];
        #pragma unroll
        for (int r = 0; r < 4; ++r) {
            #pragma unroll
            for (int m = 1; m < 16; m <<= 1)
                sum[r] += __shfl_xor(sum[r], m);
            invl[r] = 1.f / sum[r];
        }
        LGKM0();   // all P writes landed (same-wave DS in-order)
        U8 pa[2];
        #pragma unroll
        for (int s = 0; s < 2; ++s)
            pa[s].s = *(const short8*)(sbuf + swz(scrb + l15 * 64 + 32 * s + quad * 8));
        LGKM0();   // pa in regs before O overwrites scratch

        // PV; O tile (16x32) back through scratch -> phase-4 A-frag
        #pragma unroll
        for (int tp = 0; tp < 2; ++tp) {
            f32x4 o = {0.f, 0.f, 0.f, 0.f};
            #pragma unroll
            for (int s = 0; s < 2; ++s) {
                U8 vf; vf.s = *(const short8*)(sbuf + swz(VT_OFF + h * 2048 + (16 * tp + l15) * 64 + 32 * s + quad * 8));
                o = __builtin_amdgcn_mfma_f32_16x16x32_bf16(pa[s].b, vf.b, o, 0, 0, 0);
            }
            #pragma unroll
            for (int r = 0; r < 4; ++r)
                sbuf[swz(scrb + (quad * 4 + r) * 32 + 16 * tp + l15)] = f2bf(o[r] * invl[r]);
        }
        LGKM0();
        af4[h].s = *(const short8*)(sbuf + swz(scrb + l15 * 32 + quad * 8));
        LGKM0();   // retire before next h reuses scratch
    }

    // ================= Phase 4: out = O @ proj_w^T + b, direct store =================
    {
        float* op = out + (size_t)bnw * (NTOK * DIM);
        #pragma unroll
        for (int t = 0; t < 6; ++t) {
            const int col = 16 * t + l15;
            f32x4 acc = {0.f, 0.f, 0.f, 0.f};
            #pragma unroll
            for (int s = 0; s < 3; ++s) {
                U8 b; ldw<MODE>(proj_wb, proj_w, col * DIM + 32 * s + quad * 8, b);
                acc = __builtin_amdgcn_mfma_f32_16x16x32_bf16(af4[s].b, b.b, acc, 0, 0, 0);
            }
            const float pb = proj_b[col];
            #pragma unroll
            for (int r = 0; r < 4; ++r) {
                const int row = 16 * wave + quad * 4 + r;
                if (row < NTOK) op[row * DIM + col] = acc[r] + pb;
            }
        }
    }
}

extern "C" void kernel_launch(void* const* d_in, const int* in_sizes, int n_in,
                              void* d_out, int out_size, void* d_ws, size_t ws_size,
                              hipStream_t stream) {
    const float* x      = (const float*)d_in[0];
    const float* mask   = (const float*)d_in[1];
    const float* qkv_w  = (const float*)d_in[2];
    const float* qkv_b  = (const float*)d_in[3];
    const float* proj_w = (const float*)d_in[4];
    const float* proj_b = (const float*)d_in[5];
    const float* rpb    = (const float*)d_in[6];
    const int*   rel    = (const int*)d_in[7];
    float* outp         = (float*)d_out;

    int mode;
    if      (ws_size >= (size_t)WS_MODE2_NEED) mode = 2;
    else if (ws_size >= (size_t)WS_MODE1_NEED) mode = 1;
    else                                        mode = 0;

    unsigned short* qkv_wb  = (unsigned short*)d_ws;
    unsigned short* proj_wb = (unsigned short*)((char*)d_ws + PROJWB_OFFB);
    float* tab = (mode >= 1) ? (float*)((char*)d_ws + TAB_OFFB) : (float*)d_ws;

    const int npre = (mode == 2) ? FUSED_TAB_ELEMS
                   : (mode == 1) ? 3 * DIM * DIM
                                 : BIAS_TAB_ELEMS;
    prep<<<(npre + 255) / 256, 256, 0, stream>>>(rpb, rel, mask, qkv_w, proj_w,
                                                 qkv_wb, proj_wb, tab, mode);

    const int n_windows = in_sizes[0] / (NTOK * DIM);   // 4096
    if (mode == 2)
        winattn<2><<<n_windows, 256, 0, stream>>>(x, mask, qkv_w, qkv_b, proj_w, proj_b,
                                                  qkv_wb, proj_wb, tab, outp);
    else if (mode == 1)
        winattn<1><<<n_windows, 256, 0, stream>>>(x, mask, qkv_w, qkv_b, proj_w, proj_b,
                                                  qkv_wb, proj_wb, tab, outp);
    else
        winattn<0><<<n_windows, 256, 0, stream>>>(x, mask, qkv_w, qkv_b, proj_w, proj_b,
                                                  qkv_wb, proj_wb, tab, outp);
}

// Round 3
// 231.193 us; speedup vs baseline: 1.8240x; 1.1465x over previous
//
#include <hip/hip_runtime.h>
#include <math.h>

#define DIM    96
#define HEADS  3
#define NTOK   49
#define NWIN   64
#define SCALE  0.17677669529663687f

// ---- workspace layout (bytes) ----
// MODE 2: qkv_wb bf16 @0 (55296) | proj_wb bf16 @55296 (18432) | fused tab [64][3][49][49] f32 @73728 (1844352)
// MODE 1: qkv_wb bf16 @0         | proj_wb bf16 @55296         | bias tab [3][49][49] f32 @73728 (28812)
// MODE 0: bias tab [3][49][49] f32 @0 (28812)
#define PROJWB_OFFB 55296
#define TAB_OFFB    73728
#define FUSED_TAB_ELEMS (NWIN * HEADS * NTOK * NTOK)
#define BIAS_TAB_ELEMS  (HEADS * NTOK * NTOK)
#define WS_MODE2_NEED (TAB_OFFB + FUSED_TAB_ELEMS * 4)
#define WS_MODE1_NEED (TAB_OFFB + BIAS_TAB_ELEMS * 4)

// ---- LDS layout (unsigned short indices), all XOR-swizzled ----
// K   [3][64][32] @ 0      (6144)  token-major per head
// VT  [3][32][64] @ 6144   (6144)  d-major (tokens inner)
// SCR [4][1024]   @ 12288  (4096)  per-wave transpose scratch (Q/P/O)
#define K_OFF   0
#define VT_OFF  6144
#define SCR_OFF 12288
#define LDS_SHORTS 16384

typedef float  f32x4  __attribute__((ext_vector_type(4)));
typedef __bf16 bf16x8 __attribute__((ext_vector_type(8)));
typedef short  short8 __attribute__((ext_vector_type(8)));

union U8 { short8 s; bf16x8 b; };

#define LGKM0() asm volatile("s_waitcnt lgkmcnt(0)" ::: "memory")

// XOR-swizzle on short index: XOR 16B-granule bits [5:3] with 128B-line bits [8:6].
__device__ __forceinline__ int swz(int s) { return s ^ ((s >> 3) & 56); }

__device__ __forceinline__ unsigned short f2bf(float f) {
    __bf16 h = (__bf16)f;
    union { __bf16 h; unsigned short u; } v; v.h = h; return v.u;
}

__device__ __forceinline__ void ldcvt_g(const float* __restrict__ p, U8& u) {
    float4 f0 = *(const float4*)p;
    float4 f1 = *(const float4*)(p + 4);
    u.b[0] = (__bf16)f0.x; u.b[1] = (__bf16)f0.y; u.b[2] = (__bf16)f0.z; u.b[3] = (__bf16)f0.w;
    u.b[4] = (__bf16)f1.x; u.b[5] = (__bf16)f1.y; u.b[6] = (__bf16)f1.z; u.b[7] = (__bf16)f1.w;
}

// ---- prepass ----
__global__ __launch_bounds__(256)
void prep(const float* __restrict__ rpb, const int* __restrict__ rel,
          const float* __restrict__ mask,
          const float* __restrict__ qkv_w, const float* __restrict__ proj_w,
          unsigned short* __restrict__ qkv_wb, unsigned short* __restrict__ proj_wb,
          float* __restrict__ tab, int mode)
{
    int t = blockIdx.x * 256 + threadIdx.x;
    if (mode >= 1) {
        if (t < 3 * DIM * DIM) qkv_wb[t] = f2bf(qkv_w[t]);
        if (t < DIM * DIM)     proj_wb[t] = f2bf(proj_w[t]);
    }
    if (mode == 2) {
        if (t < FUSED_TAB_ELEMS) {
            int win = t / (HEADS * NTOK * NTOK);
            int rem = t - win * (HEADS * NTOK * NTOK);
            int h   = rem / (NTOK * NTOK);
            int ij  = rem - h * (NTOK * NTOK);
            tab[t] = rpb[rel[ij] * HEADS + h] + mask[win * (NTOK * NTOK) + ij];
        }
    } else if (t < BIAS_TAB_ELEMS) {
        int h = t / (NTOK * NTOK), ij = t - h * (NTOK * NTOK);
        tab[t] = rpb[rel[ij] * HEADS + h];
    }
}

// weight fragment load: bf16 from workspace (MODE>=1) or f32+convert (MODE 0)
template<int MODE>
__device__ __forceinline__ void ldw(const unsigned short* __restrict__ wb,
                                    const float* __restrict__ wf, int idx, U8& u) {
    if constexpr (MODE >= 1) u.s = *(const short8*)(wb + idx);
    else                     ldcvt_g(wf + idx, u);
}

// one 16-col GEMM tile: acc = A(16x96) * W^T cols [col..col+15]
template<int MODE>
__device__ __forceinline__ f32x4 wtile(const U8 af[3],
                                       const unsigned short* __restrict__ wb,
                                       const float* __restrict__ wf,
                                       int col, int quad) {
    f32x4 acc = {0.f, 0.f, 0.f, 0.f};
    #pragma unroll
    for (int s = 0; s < 3; ++s) {
        U8 b; ldw<MODE>(wb, wf, col * DIM + 32 * s + quad * 8, b);
        acc = __builtin_amdgcn_mfma_f32_16x16x32_bf16(af[s].b, b.b, acc, 0, 0, 0);
    }
    return acc;
}

template<int MODE>
__global__ __launch_bounds__(256, 4)
void winattn(const float* __restrict__ x,
             const float* __restrict__ mask,
             const float* __restrict__ qkv_w,
             const float* __restrict__ qkv_b,
             const float* __restrict__ proj_w,
             const float* __restrict__ proj_b,
             const unsigned short* __restrict__ qkv_wb,
             const unsigned short* __restrict__ proj_wb,
             const float* __restrict__ tab,
             float* __restrict__ out)
{
    __shared__ __align__(16) unsigned short sbuf[LDS_SHORTS];

    const int tid  = threadIdx.x;
    const int lane = tid & 63;
    const int wave = __builtin_amdgcn_readfirstlane(tid >> 6);
    const int l15  = lane & 15;
    const int quad = lane >> 4;
    const int bnw  = blockIdx.x;
    const int win  = bnw & (NWIN - 1);
    const int scrb = SCR_OFF + wave * 1024;

    // per-head-invariant softmax index math (hoisted)
    int  colc4[4]; bool cok4[4]; int rowb4[4];
    #pragma unroll
    for (int t = 0; t < 4; ++t) {
        const int colr = 16 * t + l15;
        cok4[t]  = (colr < NTOK);
        colc4[t] = cok4[t] ? colr : (NTOK - 1);
    }
    #pragma unroll
    for (int r = 0; r < 4; ++r) {
        const int rowr = 16 * wave + quad * 4 + r;
        rowb4[r] = ((rowr < NTOK) ? rowr : (NTOK - 1)) * NTOK;
    }
    const float* fmh[3];
    #pragma unroll
    for (int h = 0; h < 3; ++h)
        fmh[h] = (MODE == 2) ? (tab + (size_t)(win * HEADS + h) * (NTOK * NTOK))
                             : (tab + h * (NTOK * NTOK));
    const float* mw = mask + (size_t)win * (NTOK * NTOK);

    // ================= Phase 1: QKV = x @ qkv_w^T + b =================
    U8 af[3];
    {
        const float* xw = x + (size_t)bnw * (NTOK * DIM);
        const int arow = 16 * wave + l15;
        const bool av = (arow < NTOK);
        #pragma unroll
        for (int s = 0; s < 3; ++s) {
            if (av) ldcvt_g(xw + arow * DIM + 32 * s + quad * 8, af[s]);
            else {
                #pragma unroll
                for (int j = 0; j < 8; ++j) af[s].b[j] = (__bf16)0.0f;
            }
        }
    }

    U8 qfrag[3];
    // Groups: {Q(h) halves + 3 K-or-6 V tiles} -> LGKM0 -> qfrag read -> LGKM0
    #pragma unroll
    for (int g = 0; g < 3; ++g) {
        // Q tiles for head g -> per-wave scratch
        #pragma unroll
        for (int half = 0; half < 2; ++half) {
            const int col = 16 * (2 * g + half) + l15;
            f32x4 acc = wtile<MODE>(af, qkv_wb, qkv_w, col, quad);
            const float bb = qkv_b[col];
            #pragma unroll
            for (int r = 0; r < 4; ++r)
                sbuf[swz(scrb + (quad * 4 + r) * 32 + half * 16 + l15)] =
                    f2bf((acc[r] + bb) * SCALE);
        }
        if (g < 2) {
            // 3 K tiles interleaved into this scheduling region
            #pragma unroll
            for (int tk = 3 * g; tk < 3 * g + 3; ++tk) {
                const int col = 16 * (tk + 6) + l15;
                f32x4 acc = wtile<MODE>(af, qkv_wb, qkv_w, col, quad);
                const float bb = qkv_b[col];
                const int c = col - DIM, h = c >> 5, d = c & 31;
                #pragma unroll
                for (int r = 0; r < 4; ++r) {
                    const int row = 16 * wave + quad * 4 + r;
                    sbuf[swz(K_OFF + h * 2048 + row * 32 + d)] = f2bf(acc[r] + bb);
                }
            }
        } else {
            // all 6 V tiles in the last region
            #pragma unroll
            for (int tv = 0; tv < 6; ++tv) {
                const int col = 16 * (tv + 12) + l15;
                f32x4 acc = wtile<MODE>(af, qkv_wb, qkv_w, col, quad);
                const float bb = qkv_b[col];
                const int c = col - 2 * DIM, h = c >> 5, d = c & 31;
                const int row0 = 16 * wave + quad * 4;
                ushort4 pk;
                pk.x = f2bf(acc[0] + bb); pk.y = f2bf(acc[1] + bb);
                pk.z = f2bf(acc[2] + bb); pk.w = f2bf(acc[3] + bb);
                *(ushort4*)(sbuf + swz(VT_OFF + h * 2048 + d * 64 + row0)) = pk;
            }
        }
        LGKM0();
        qfrag[g].s = *(const short8*)(sbuf + swz(scrb + l15 * 32 + quad * 8));
        LGKM0();   // retire read before next group reuses scratch
    }

    // prefetch head-0 tab into regs; latency hidden under the barrier drain
    float tabv[2][4][4];
    #pragma unroll
    for (int t = 0; t < 4; ++t)
        #pragma unroll
        for (int r = 0; r < 4; ++r) {
            float v = fmh[0][rowb4[r] + colc4[t]];
            if constexpr (MODE != 2) v += mw[rowb4[r] + colc4[t]];
            tabv[0][t][r] = v;
        }

    __syncthreads();   // the ONLY barrier: K and VT visible to all waves

    // ====== Phase 2+3 (per head): S = QK^T + tab, neg-softmax, O = P V ======
    U8 af4[3];
    U8 pw0[3];   // phase-4 tile-0 weight prefetch
    #pragma unroll
    for (int h = 0; h < 3; ++h) {
        f32x4 st[4];
        #pragma unroll
        for (int t = 0; t < 4; ++t) {
            U8 kf; kf.s = *(const short8*)(sbuf + swz(K_OFF + h * 2048 + (16 * t + l15) * 32 + quad * 8));
            f32x4 z = {0.f, 0.f, 0.f, 0.f};
            st[t] = __builtin_amdgcn_mfma_f32_16x16x32_bf16(qfrag[h].b, kf.b, z, 0, 0, 0);
        }
        float sv[4][4];
        float mx[4] = {-1e30f, -1e30f, -1e30f, -1e30f};
        #pragma unroll
        for (int t = 0; t < 4; ++t)
            #pragma unroll
            for (int r = 0; r < 4; ++r) {
                float s = st[t][r] + tabv[h & 1][t][r];
                sv[t][r] = s;
                float aa = cok4[t] ? fabsf(s) : -1e30f;
                mx[r] = fmaxf(mx[r], aa);
            }
        // prefetch next head's tab before entering the LGKM0-serialized tail
        if (h < 2) {
            #pragma unroll
            for (int t = 0; t < 4; ++t)
                #pragma unroll
                for (int r = 0; r < 4; ++r) {
                    float v = fmh[h + 1][rowb4[r] + colc4[t]];
                    if constexpr (MODE != 2) v += mw[rowb4[r] + colc4[t]];
                    tabv[(h + 1) & 1][t][r] = v;
                }
        }
        #pragma unroll
        for (int r = 0; r < 4; ++r)
            #pragma unroll
            for (int m = 1; m < 16; m <<= 1)
                mx[r] = fmaxf(mx[r], __shfl_xor(mx[r], m));
        float sum[4] = {0.f, 0.f, 0.f, 0.f};
        #pragma unroll
        for (int t = 0; t < 4; ++t)
            #pragma unroll
            for (int r = 0; r < 4; ++r) {
                const float s = sv[t][r];
                const float e = cok4[t] ? __expf(fabsf(s) - mx[r]) : 0.f;
                sum[r] += e;
                const float p = (s > 0.f) ? e : ((s < 0.f) ? -e : 0.f);
                sbuf[swz(scrb + (quad * 4 + r) * 64 + 16 * t + l15)] = f2bf(p);
            }
        float invl[4];
        #pragma unroll
        for (int r = 0; r < 4; ++r) {
            #pragma unroll
            for (int m = 1; m < 16; m <<= 1)
                sum[r] += __shfl_xor(sum[r], m);
            invl[r] = 1.f / sum[r];
        }
        LGKM0();   // P writes landed
        U8 pa[2];
        #pragma unroll
        for (int s = 0; s < 2; ++s)
            pa[s].s = *(const short8*)(sbuf + swz(scrb + l15 * 64 + 32 * s + quad * 8));
        LGKM0();   // pa in regs before O overwrites scratch

        #pragma unroll
        for (int tp = 0; tp < 2; ++tp) {
            f32x4 o = {0.f, 0.f, 0.f, 0.f};
            #pragma unroll
            for (int s = 0; s < 2; ++s) {
                U8 vf; vf.s = *(const short8*)(sbuf + swz(VT_OFF + h * 2048 + (16 * tp + l15) * 64 + 32 * s + quad * 8));
                o = __builtin_amdgcn_mfma_f32_16x16x32_bf16(pa[s].b, vf.b, o, 0, 0, 0);
            }
            #pragma unroll
            for (int r = 0; r < 4; ++r)
                sbuf[swz(scrb + (quad * 4 + r) * 32 + 16 * tp + l15)] = f2bf(o[r] * invl[r]);
        }
        if (h == 2) {   // prefetch phase-4 tile 0 weights before final waits
            #pragma unroll
            for (int s = 0; s < 3; ++s)
                ldw<MODE>(proj_wb, proj_w, l15 * DIM + 32 * s + quad * 8, pw0[s]);
        }
        LGKM0();
        af4[h].s = *(const short8*)(sbuf + swz(scrb + l15 * 32 + quad * 8));
        LGKM0();   // retire before next h reuses scratch
    }

    // ================= Phase 4: out = O @ proj_w^T + b, nt stores =================
    {
        float* op = out + (size_t)bnw * (NTOK * DIM);
        #pragma unroll
        for (int t = 0; t < 6; ++t) {
            const int col = 16 * t + l15;
            f32x4 acc = {0.f, 0.f, 0.f, 0.f};
            #pragma unroll
            for (int s = 0; s < 3; ++s) {
                U8 b;
                if (t == 0) b = pw0[s];
                else        ldw<MODE>(proj_wb, proj_w, col * DIM + 32 * s + quad * 8, b);
                acc = __builtin_amdgcn_mfma_f32_16x16x32_bf16(af4[s].b, b.b, acc, 0, 0, 0);
            }
            const float pb = proj_b[col];
            #pragma unroll
            for (int r = 0; r < 4; ++r) {
                const int row = 16 * wave + quad * 4 + r;
                if (row < NTOK)
                    __builtin_nontemporal_store(acc[r] + pb, op + row * DIM + col);
            }
        }
    }
}

extern "C" void kernel_launch(void* const* d_in, const int* in_sizes, int n_in,
                              void* d_out, int out_size, void* d_ws, size_t ws_size,
                              hipStream_t stream) {
    const float* x      = (const float*)d_in[0];
    const float* mask   = (const float*)d_in[1];
    const float* qkv_w  = (const float*)d_in[2];
    const float* qkv_b  = (const float*)d_in[3];
    const float* proj_w = (const float*)d_in[4];
    const float* proj_b = (const float*)d_in[5];
    const float* rpb    = (const float*)d_in[6];
    const int*   rel    = (const int*)d_in[7];
    float* outp         = (float*)d_out;

    int mode;
    if      (ws_size >= (size_t)WS_MODE2_NEED) mode = 2;
    else if (ws_size >= (size_t)WS_MODE1_NEED) mode = 1;
    else                                        mode = 0;

    unsigned short* qkv_wb  = (unsigned short*)d_ws;
    unsigned short* proj_wb = (unsigned short*)((char*)d_ws + PROJWB_OFFB);
    float* tab = (mode >= 1) ? (float*)((char*)d_ws + TAB_OFFB) : (float*)d_ws;

    const int npre = (mode == 2) ? FUSED_TAB_ELEMS
                   : (mode == 1) ? 3 * DIM * DIM
                                 : BIAS_TAB_ELEMS;
    prep<<<(npre + 255) / 256, 256, 0, stream>>>(rpb, rel, mask, qkv_w, proj_w,
                                                 qkv_wb, proj_wb, tab, mode);

    const int n_windows = in_sizes[0] / (NTOK * DIM);   // 4096
    if (mode == 2)
        winattn<2><<<n_windows, 256, 0, stream>>>(x, mask, qkv_w, qkv_b, proj_w, proj_b,
                                                  qkv_wb, proj_wb, tab, outp);
    else if (mode == 1)
        winattn<1><<<n_windows, 256, 0, stream>>>(x, mask, qkv_w, qkv_b, proj_w, proj_b,
                                                  qkv_wb, proj_wb, tab, outp);
    else
        winattn<0><<<n_windows, 256, 0, stream>>>(x, mask, qkv_w, qkv_b, proj_w, proj_b,
                                                  qkv_wb, proj_wb, tab, outp);
}